// Round 2
// baseline (40.569 us; speedup 1.0000x reference)
//
#include <hip/hip_runtime.h>
#include <math.h>

#define IN_CH   2048
#define OUT_CH  1000
#define NROWS   8192
#define EPS_F   1e-8

// ---------------------------------------------------------------------------
// Kernel 1: deterministic per-block partial sum of squares over all of x.
// 2048 blocks x 256 threads, 8 float4 per thread => exactly 8192*2048 floats.
// ---------------------------------------------------------------------------
__global__ __launch_bounds__(256) void sumsq_kernel(const float4* __restrict__ x4,
                                                    float* __restrict__ partials) {
    const int t = threadIdx.x;
    const long long base = (long long)blockIdx.x * 2048 + t;
    float acc = 0.f;
#pragma unroll
    for (int k = 0; k < 8; ++k) {
        float4 v = x4[base + k * 256];
        acc += v.x * v.x + v.y * v.y + v.z * v.z + v.w * v.w;
    }
    // wave (64-lane) butterfly reduce
#pragma unroll
    for (int s = 32; s > 0; s >>= 1) acc += __shfl_xor(acc, s);
    __shared__ float wsum[4];
    const int lane = t & 63, w = t >> 6;
    if (lane == 0) wsum[w] = acc;
    __syncthreads();
    if (t == 0) partials[blockIdx.x] = (wsum[0] + wsum[1]) + (wsum[2] + wsum[3]);
}

// ---------------------------------------------------------------------------
// Kernel 2: reduce 2048 partials (double accum), emit factor = -scale/norm.
// ---------------------------------------------------------------------------
__global__ __launch_bounds__(256) void finalize_kernel(const float* __restrict__ partials,
                                                       const float* __restrict__ scale,
                                                       float* __restrict__ factor) {
    const int t = threadIdx.x;
    double acc = 0.0;
#pragma unroll
    for (int k = 0; k < 8; ++k) acc += (double)partials[t + k * 256];
#pragma unroll
    for (int s = 32; s > 0; s >>= 1) acc += __shfl_xor(acc, s);
    __shared__ double wsum[4];
    const int lane = t & 63, w = t >> 6;
    if (lane == 0) wsum[w] = acc;
    __syncthreads();
    if (t == 0) {
        double total = (wsum[0] + wsum[1]) + (wsum[2] + wsum[3]);
        double norm = sqrt(total) + (double)EPS_F;
        *factor = (float)(-((double)(*scale)) / norm);
    }
}

// ---------------------------------------------------------------------------
// Kernel 3: per-row FWHT(2048), keep first 1000 outputs, scale by factor.
// One block (256 threads) per row. Thread t holds i-bits: {0,1}=float4 lane,
// {10}=which half (register bits), {2..7}=lane (shfl_xor), {8,9}=wave (LDS).
//   a[half*4 + rlow]  <->  element i = half*1024 + 4*t + rlow
// FWHT butterfly stages commute, so we process register bits, then lane bits,
// then cross-wave bits; thread t register (half,rlow) ends holding
// y[half*1024 + 4t + rlow].
// ---------------------------------------------------------------------------
__global__ __launch_bounds__(256) void fwht_kernel(const float* __restrict__ x,
                                                   const float* __restrict__ factorp,
                                                   float* __restrict__ out) {
    const int row = blockIdx.x;
    const int t = threadIdx.x;

    const float4* xr = (const float4*)(x + (size_t)row * IN_CH);
    float4 u0 = xr[t];         // elements 4t .. 4t+3        (half 0)
    float4 u1 = xr[t + 256];   // elements 1024+4t .. 4t+3   (half 1)
    float a[8] = {u0.x, u0.y, u0.z, u0.w, u1.x, u1.y, u1.z, u1.w};

    // --- register-resident bits: FWHT_8 over a[] (i-bits 0,1,10) ---
#pragma unroll
    for (int s = 1; s < 8; s <<= 1) {
#pragma unroll
        for (int r = 0; r < 8; ++r) {
            if (!(r & s)) {
                float u = a[r], v = a[r | s];
                a[r] = u + v;
                a[r | s] = u - v;
            }
        }
    }

    // --- lane bits (i-bits 2..7 == t-bits 0..5) via shfl_xor ---
#pragma unroll
    for (int s = 1; s <= 32; s <<= 1) {
#pragma unroll
        for (int r = 0; r < 8; ++r) {
            float o = __shfl_xor(a[r], s);
            a[r] = (t & s) ? (o - a[r]) : (a[r] + o);
        }
    }

    // --- cross-wave bits (t-bits 6,7) via one LDS exchange (FWHT_4) ---
    __shared__ float lds[8][256];
#pragma unroll
    for (int r = 0; r < 8; ++r) lds[r][t] = a[r];
    __syncthreads();
    const int l6 = t & 63, w = t >> 6;
    const float s1 = (w & 1) ? -1.f : 1.f;
    const float s2 = (w & 2) ? -1.f : 1.f;
    const float s3 = s1 * s2;
#pragma unroll
    for (int r = 0; r < 8; ++r) {
        float v0 = lds[r][l6];
        float v1 = lds[r][l6 + 64];
        float v2 = lds[r][l6 + 128];
        float v3 = lds[r][l6 + 192];
        a[r] = v0 + s1 * v1 + s2 * v2 + s3 * v3;
    }

    // --- epilogue: y[o] for o = 4t+rlow (half 0), keep o < 1000 ---
    const float f = *factorp;
    if (t < 250) {  // 4t+3 <= 999
        float4 o0 = make_float4(a[0] * f, a[1] * f, a[2] * f, a[3] * f);
        float4* orow = (float4*)(out + (size_t)row * OUT_CH);
        orow[t] = o0;
    }
}

extern "C" void kernel_launch(void* const* d_in, const int* in_sizes, int n_in,
                              void* d_out, int out_size, void* d_ws, size_t ws_size,
                              hipStream_t stream) {
    const float* x     = (const float*)d_in[0];
    // d_in[1] = proj — unused: it is the Sylvester Hadamard matrix by
    // construction, so the einsum is a Fast Walsh-Hadamard Transform.
    const float* scale = (const float*)d_in[2];
    float* out = (float*)d_out;

    float* partials = (float*)d_ws;        // 2048 floats
    float* factor   = partials + 2048;     // 1 float

    sumsq_kernel<<<2048, 256, 0, stream>>>((const float4*)x, partials);
    finalize_kernel<<<1, 256, 0, stream>>>(partials, scale, factor);
    fwht_kernel<<<NROWS, 256, 0, stream>>>(x, factor, out);
}

// Round 3
// 32.130 us; speedup vs baseline: 1.2626x; 1.2626x over previous
//
#include <hip/hip_runtime.h>
#include <math.h>

#define IN_CH   2048
#define OUT_CH  1000
#define NROWS   8192

// ---------------------------------------------------------------------------
// Kernel 1: deterministic per-block partial sum of squares over all of x.
// 2048 blocks x 256 threads, 8 float4 per thread => exactly 8192*2048 floats.
// HBM-bound: 64 MB read ~= 10.3 us. At roofline.
// ---------------------------------------------------------------------------
__global__ __launch_bounds__(256) void sumsq_kernel(const float4* __restrict__ x4,
                                                    float* __restrict__ partials) {
    const int t = threadIdx.x;
    const long long base = (long long)blockIdx.x * 2048 + t;
    float acc = 0.f;
#pragma unroll
    for (int k = 0; k < 8; ++k) {
        float4 v = x4[base + k * 256];
        acc += v.x * v.x + v.y * v.y + v.z * v.z + v.w * v.w;
    }
#pragma unroll
    for (int s = 32; s > 0; s >>= 1) acc += __shfl_xor(acc, s);
    __shared__ float wsum[4];
    const int lane = t & 63, w = t >> 6;
    if (lane == 0) wsum[w] = acc;
    __syncthreads();
    if (t == 0) partials[blockIdx.x] = (wsum[0] + wsum[1]) + (wsum[2] + wsum[3]);
}

#define BFLY(A, i, j) { float u_ = A[i], v_ = A[j]; A[i] = u_ + v_; A[j] = u_ - v_; }
// radix-8 butterfly over an 8-register group (3 index bits)
#define RADIX8(A) \
    BFLY(A,0,1) BFLY(A,2,3) BFLY(A,4,5) BFLY(A,6,7) \
    BFLY(A,0,2) BFLY(A,1,3) BFLY(A,4,6) BFLY(A,5,7) \
    BFLY(A,0,4) BFLY(A,1,5) BFLY(A,2,6) BFLY(A,3,7)

// ---------------------------------------------------------------------------
// Kernel 2: per-row FWHT(2048) via 4 register-resident butterfly rounds on
// element-index bit groups {0,1,10}, {2,3,4}, {5,6,7}, {8,9}, connected by
// 3 LDS exchanges. Each LDS buffer uses a bit-permuted layout (pi) chosen so
// that READS are 2x ds_read_b128 with perfect 32-bank coverage per 8-lane
// group, and WRITES are conflict-free b32 pairs (ds_write2_b32-mergeable,
// +64-word offsets). Also computes the scale factor from kernel1's partials
// (identical double-precision reduction in every block => deterministic).
// ---------------------------------------------------------------------------
__global__ __launch_bounds__(256) void fwht_kernel(const float* __restrict__ x,
                                                   const float* __restrict__ partials,
                                                   const float* __restrict__ scale,
                                                   float* __restrict__ out) {
    const int row = blockIdx.x;
    const int t = threadIdx.x;

    __shared__ __align__(16) float bufA[2048];
    __shared__ __align__(16) float bufB[2048];
    __shared__ double wsum[4];

    // issue the row loads early (hide HBM/L3 latency under factor reduce)
    const float4* xr = (const float4*)(x + (size_t)row * IN_CH);
    const float4 u0 = xr[t];        // elems 4t+{0..3},   e10=0
    const float4 u1 = xr[t + 256];  // elems 1024+4t+{0..3}, e10=1

    // ---- factor = -scale / (||x|| + eps), same reduction order per block ----
    const float4* p4 = (const float4*)partials;
    const float4 q0 = p4[2 * t], q1 = p4[2 * t + 1];
    double acc = (double)q0.x + q0.y;
    acc += q0.z; acc += q0.w; acc += q1.x; acc += q1.y; acc += q1.z; acc += q1.w;
#pragma unroll
    for (int s = 32; s > 0; s >>= 1) acc += __shfl_xor(acc, s);
    if ((t & 63) == 0) wsum[t >> 6] = acc;
    __syncthreads();
    const double total = (wsum[0] + wsum[1]) + (wsum[2] + wsum[3]);
    const float f = (float)(-((double)(*scale)) / (sqrt(total) + 1e-8));

    const int t0 = t & 1, t1 = (t >> 1) & 1, t2 = (t >> 2) & 1, t3 = (t >> 3) & 1;
    const int t4 = (t >> 4) & 1, t5 = (t >> 5) & 1, t6 = (t >> 6) & 1, t7 = (t >> 7) & 1;

    // ---- round 0: regs hold e-bits {0,1,10}; thread t owns e{2..9}=t{0..7} ----
    float a[8] = {u0.x, u0.y, u0.z, u0.w, u1.x, u1.y, u1.z, u1.w};
    RADIX8(a)

    // X1 -> bufA, layout pi1: s0=e2 s1=e3 s2=e5 s3=e6 s4=e7 s5=e4
    //                         s6=e0 s7=e1 s8=e8 s9=e9 s10=e10
    {
        const int bW1 = t0 + 2 * t1 + 4 * t3 + 8 * t4 + 16 * t5 + 32 * t2 + 256 * t6 + 512 * t7;
        bufA[bW1 +    0] = a[0]; bufA[bW1 +   64] = a[1];
        bufA[bW1 +  128] = a[2]; bufA[bW1 +  192] = a[3];
        bufA[bW1 + 1024] = a[4]; bufA[bW1 + 1088] = a[5];
        bufA[bW1 + 1152] = a[6]; bufA[bW1 + 1216] = a[7];
    }
    __syncthreads();

    // ---- round 1: regs {2,3,4}; thread map e5=t0 e6=t1 e7=t2 e0=t3 e1=t4 e8=t5 e9=t6 e10=t7
    float b[8];
    {
        const int bR1 = 4 * (t & 7) + 64 * (t >> 3);
        const float4 v0 = *(const float4*)&bufA[bR1];
        const float4 v1 = *(const float4*)&bufA[bR1 + 32];
        b[0] = v0.x; b[1] = v0.y; b[2] = v0.z; b[3] = v0.w;
        b[4] = v1.x; b[5] = v1.y; b[6] = v1.z; b[7] = v1.w;
    }
    RADIX8(b)

    // X2 -> bufB, layout pi2: s0=e5 s1=e6 s2=e0 s3=e1 s4=e8 s5=e7
    //                         s6=e2 s7=e3 s8=e4 s9=e9 s10=e10
    {
        const int bW2 = t0 + 2 * t1 + 4 * t3 + 8 * t4 + 16 * t5 + 32 * t2 + 512 * t6 + 1024 * t7;
#pragma unroll
        for (int r = 0; r < 8; ++r) bufB[bW2 + 64 * r] = b[r];
    }
    __syncthreads();

    // ---- round 2: regs {5,6,7}; thread map e0=t0 e1=t1 e8=t2 e9=t3 e2=t4 e3=t5 e4=t6 e10=t7
    float c[8];
    {
        const int bR2 = 4 * (t & 7) + 512 * t3 + 64 * t4 + 128 * t5 + 256 * t6 + 1024 * t7;
        const float4 v0 = *(const float4*)&bufB[bR2];
        const float4 v1 = *(const float4*)&bufB[bR2 + 32];
        c[0] = v0.x; c[1] = v0.y; c[2] = v0.z; c[3] = v0.w;
        c[4] = v1.x; c[5] = v1.y; c[6] = v1.z; c[7] = v1.w;
    }
    RADIX8(c)

    // X3 -> bufA (safe: all R1 reads precede the bar after W2), layout pi3:
    // s0=e8 s1=e9 s2=e0 s3=e1 s4=e2 s5=e10 s6=e5 s7=e6 s8=e7 s9=e3 s10=e4
    {
        const int bW3 = t2 + 2 * t3 + 4 * t0 + 8 * t1 + 16 * t4 + 32 * t7 + 512 * t5 + 1024 * t6;
#pragma unroll
        for (int r = 0; r < 8; ++r) bufA[bW3 + 64 * r] = c[r];
    }
    __syncthreads();

    // ---- round 3: regs {8,9,10}; thread map e_i = t_i (i=0..7) ----
    float d[8];
    {
        const int bR3 = 4 * (t & 7) + 512 * t3 + 1024 * t4 + 64 * t5 + 128 * t6 + 256 * t7;
        const float4 v0 = *(const float4*)&bufA[bR3];
        const float4 v1 = *(const float4*)&bufA[bR3 + 32];
        d[0] = v0.x; d[1] = v0.y; d[2] = v0.z; d[3] = v0.w;
        d[4] = v1.x; d[5] = v1.y; d[6] = v1.z; d[7] = v1.w;
    }
    // radix-4 on bits {8,9} within each e10 half (bit 10 already transformed)
    BFLY(d, 0, 1) BFLY(d, 2, 3) BFLY(d, 0, 2) BFLY(d, 1, 3)
    BFLY(d, 4, 5) BFLY(d, 6, 7) BFLY(d, 4, 6) BFLY(d, 5, 7)

    // ---- store: reg k (k<4, e10=0) holds y[t + 256k]; keep e < 1000 ----
    float* orow = out + (size_t)row * OUT_CH;
    orow[t]       = f * d[0];
    orow[t + 256] = f * d[1];
    orow[t + 512] = f * d[2];
    if (t < 232) orow[t + 768] = f * d[3];
}

extern "C" void kernel_launch(void* const* d_in, const int* in_sizes, int n_in,
                              void* d_out, int out_size, void* d_ws, size_t ws_size,
                              hipStream_t stream) {
    const float* x     = (const float*)d_in[0];
    // d_in[1] = proj — unused: it is the Sylvester Hadamard matrix by
    // construction, so the einsum is a Fast Walsh-Hadamard Transform.
    const float* scale = (const float*)d_in[2];
    float* out = (float*)d_out;

    float* partials = (float*)d_ws;  // 2048 floats

    sumsq_kernel<<<2048, 256, 0, stream>>>((const float4*)x, partials);
    fwht_kernel<<<NROWS, 256, 0, stream>>>(x, partials, scale, out);
}